// Round 1
// baseline (554.629 us; speedup 1.0000x reference)
//
#include <hip/hip_runtime.h>
#include <hip/hip_bf16.h>
#include <math.h>

typedef __attribute__((ext_vector_type(8))) short bf16x8;
typedef __attribute__((ext_vector_type(4))) short s16x4;
typedef __attribute__((ext_vector_type(4))) float f32x4;

static __device__ __forceinline__ short f2bf(float f) {
    union { float f; unsigned u; } v; v.f = f;
    unsigned r = v.u + 0x7FFFu + ((v.u >> 16) & 1u);
    return (short)(r >> 16);
}

// ---------------------------------------------------------------------------
// Weight transpose + fp32->bf16:  WT[n][k] = bf16(W[k][n]),  512x512 each
// ---------------------------------------------------------------------------
__global__ __launch_bounds__(256) void wt_kernel(
    const float* __restrict__ Wq, const float* __restrict__ Wk,
    const float* __restrict__ Wv, const float* __restrict__ Wo,
    short* __restrict__ WqT, short* __restrict__ WkT,
    short* __restrict__ WvT, short* __restrict__ WoT)
{
    __shared__ short lds[64][65];
    const float* src; short* dst;
    if (blockIdx.z == 0)      { src = Wq; dst = WqT; }
    else if (blockIdx.z == 1) { src = Wk; dst = WkT; }
    else if (blockIdx.z == 2) { src = Wv; dst = WvT; }
    else                      { src = Wo; dst = WoT; }
    const int kb = blockIdx.x * 64, nb = blockIdx.y * 64;
    const int t = threadIdx.x;
    const int c = t & 63, r0 = t >> 6;
#pragma unroll
    for (int rr = 0; rr < 16; ++rr) {
        const int r = r0 * 16 + rr;
        lds[c][r] = f2bf(src[(size_t)(kb + r) * 512 + nb + c]);
    }
    __syncthreads();
#pragma unroll
    for (int rr = 0; rr < 16; ++rr) {
        const int n = r0 * 16 + rr;
        dst[(size_t)(nb + n) * 512 + kb + c] = lds[n][c];
    }
}

// ---------------------------------------------------------------------------
// Memory slots: Kb rows 1024..1063 = sqrt(64)*memK, Vb rows = sqrt(40)*memV
// layouts: Kb/Vb are [b*8+h][1064][64] bf16
// ---------------------------------------------------------------------------
__global__ __launch_bounds__(256) void mem_kernel(
    const float* __restrict__ memK, const float* __restrict__ memV,
    short* __restrict__ Kb, short* __restrict__ Vb)
{
    const int idx = blockIdx.x * 256 + threadIdx.x;
    if (idx >= 16 * 8 * 40 * 64) return;
    const int d = idx & 63;
    const int m = (idx >> 6) % 40;
    const int h = (idx / 2560) & 7;
    const int b = idx / 20480;
    const int src = m * 512 + h * 64 + d;
    const size_t dstrow = ((size_t)(b * 8 + h) * 1064 + 1024 + m);
    Kb[dstrow * 64 + d] = f2bf(8.0f * memK[src]);
    Vb[dstrow * 64 + d] = f2bf(sqrtf(40.0f) * memV[src]);
}

// ---------------------------------------------------------------------------
// Projection GEMM: out[b,h,n,d] (bf16) = A(fp32 [16384][512]) @ BT^T + bias
// BT is bf16 [512 n][512 k].  128x128 tile, BK=32, 4 waves x (64x64).
// ---------------------------------------------------------------------------
__global__ __launch_bounds__(256) void proj_gemm(
    const float* __restrict__ A, const short* __restrict__ BT,
    const float* __restrict__ bias, short* __restrict__ out, int OUTROWS)
{
    __shared__ short As[128][40];
    __shared__ short Bs[128][40];
    const int t = threadIdx.x;
    const int lane = t & 63, w = t >> 6;
    const int wr = w >> 1, wc = w & 1;
    const int l16 = lane & 15, g4 = lane >> 4;
    const int m0 = blockIdx.y * 128, n0 = blockIdx.x * 128;

    f32x4 acc[4][4];
#pragma unroll
    for (int i = 0; i < 4; ++i)
#pragma unroll
        for (int j = 0; j < 4; ++j) acc[i][j] = (f32x4){0.f, 0.f, 0.f, 0.f};

    const int sar = t >> 3, sak = (t & 7) * 4;
    const int sbr = t >> 2, sbk = (t & 3) * 8;

    for (int kt = 0; kt < 16; ++kt) {
        const int k0 = kt * 32;
#pragma unroll
        for (int rr = 0; rr < 4; ++rr) {
            const int row = sar + rr * 32;
            const float4 v = *reinterpret_cast<const float4*>(&A[(size_t)(m0 + row) * 512 + k0 + sak]);
            s16x4 bv; bv.x = f2bf(v.x); bv.y = f2bf(v.y); bv.z = f2bf(v.z); bv.w = f2bf(v.w);
            *reinterpret_cast<s16x4*>(&As[row][sak]) = bv;
        }
#pragma unroll
        for (int nn = 0; nn < 2; ++nn) {
            const int n = sbr + nn * 64;
            *reinterpret_cast<bf16x8*>(&Bs[n][sbk]) =
                *reinterpret_cast<const bf16x8*>(&BT[(size_t)(n0 + n) * 512 + k0 + sbk]);
        }
        __syncthreads();
        bf16x8 af[4], bfr[4];
#pragma unroll
        for (int mi = 0; mi < 4; ++mi)
            af[mi] = *reinterpret_cast<const bf16x8*>(&As[wr * 64 + mi * 16 + l16][g4 * 8]);
#pragma unroll
        for (int ni = 0; ni < 4; ++ni)
            bfr[ni] = *reinterpret_cast<const bf16x8*>(&Bs[wc * 64 + ni * 16 + l16][g4 * 8]);
#pragma unroll
        for (int mi = 0; mi < 4; ++mi)
#pragma unroll
            for (int ni = 0; ni < 4; ++ni)
                acc[mi][ni] = __builtin_amdgcn_mfma_f32_16x16x32_bf16(af[mi], bfr[ni], acc[mi][ni], 0, 0, 0);
        __syncthreads();
    }
#pragma unroll
    for (int mi = 0; mi < 4; ++mi) {
#pragma unroll
        for (int ni = 0; ni < 4; ++ni) {
            const int col = n0 + wc * 64 + ni * 16 + l16;
            const int h = col >> 6, d = col & 63;
            const float bb = bias[col];
#pragma unroll
            for (int r = 0; r < 4; ++r) {
                const int rowg = m0 + wr * 64 + mi * 16 + g4 * 4 + r;
                const int b = rowg >> 10, n = rowg & 1023;
                out[(((size_t)b * 8 + h) * OUTROWS + n) * 64 + d] = f2bf(acc[mi][ni][r] + bb);
            }
        }
    }
}

// ---------------------------------------------------------------------------
// Flash attention: grid (h=8, qtile=16, b=16), 4 waves, 64 q-rows/block.
// KVBLK=32, 34 tiles (1088 padded, mask >=1064).  aw modulates k<1024 logits.
// ---------------------------------------------------------------------------
__global__ __launch_bounds__(256) void attn_kernel(
    const short* __restrict__ Qb, const short* __restrict__ Kb,
    const short* __restrict__ Vb, const float* __restrict__ aw,
    short* __restrict__ AO)
{
    __shared__ short Ks[32][72];
    __shared__ short Vs[64][40];       // transposed: [dv][k]
    __shared__ short Ps[4][16][40];    // wave-private P tiles

    const int h = blockIdx.x, qt = blockIdx.y, b = blockIdx.z;
    const int bh = b * 8 + h;
    const int t = threadIdx.x;
    const int lane = t & 63, w = t >> 6;
    const int l16 = lane & 15, g4 = lane >> 4;
    const int qrow0 = qt * 64 + w * 16;

    bf16x8 qf0, qf1;
    {
        const short* qp = Qb + ((size_t)bh * 1024 + qrow0 + l16) * 64 + g4 * 8;
        qf0 = *reinterpret_cast<const bf16x8*>(qp);
        qf1 = *reinterpret_cast<const bf16x8*>(qp + 32);
    }

    f32x4 O[4];
#pragma unroll
    for (int i = 0; i < 4; ++i) O[i] = (f32x4){0.f, 0.f, 0.f, 0.f};
    float m_r[4] = {-1e30f, -1e30f, -1e30f, -1e30f};
    float l_r[4] = {0.f, 0.f, 0.f, 0.f};

    const int skr = t >> 3, skc = (t & 7) * 8;   // K staging
    const int svd = t & 63, svk = (t >> 6) * 8;  // V^T staging

    for (int kt = 0; kt < 34; ++kt) {
        const int kb = kt * 32;
        {   // stage K tile [32][64]
            const int rg = kb + skr;
            bf16x8 kv = {0, 0, 0, 0, 0, 0, 0, 0};
            if (rg < 1064)
                kv = *reinterpret_cast<const bf16x8*>(&Kb[((size_t)bh * 1064 + rg) * 64 + skc]);
            *reinterpret_cast<bf16x8*>(&Ks[skr][skc]) = kv;
        }
        {   // stage V^T tile [64 dv][32 k]
            bf16x8 vv = {0, 0, 0, 0, 0, 0, 0, 0};
#pragma unroll
            for (int j = 0; j < 8; ++j) {
                const int rg = kb + svk + j;
                if (rg < 1064) vv[j] = Vb[((size_t)bh * 1064 + rg) * 64 + svd];
            }
            *reinterpret_cast<bf16x8*>(&Vs[svd][svk]) = vv;
        }
        __syncthreads();

        // QK^T: S[sub] covers k cols kb+sub*16+l16, q rows qrow0+g4*4+reg
        f32x4 S[2];
#pragma unroll
        for (int sub = 0; sub < 2; ++sub) {
            bf16x8 kf0 = *reinterpret_cast<const bf16x8*>(&Ks[sub * 16 + l16][g4 * 8]);
            bf16x8 kf1 = *reinterpret_cast<const bf16x8*>(&Ks[sub * 16 + l16][32 + g4 * 8]);
            f32x4 z = {0.f, 0.f, 0.f, 0.f};
            z = __builtin_amdgcn_mfma_f32_16x16x32_bf16(qf0, kf0, z, 0, 0, 0);
            S[sub] = __builtin_amdgcn_mfma_f32_16x16x32_bf16(qf1, kf1, z, 0, 0, 0);
        }
        const bool useaw = (kb < 1024);
        const bool tail = (kb + 32 > 1064);
        float p0v[4], p1v[4], corr[4];
#pragma unroll
        for (int r = 0; r < 4; ++r) {
            float s0 = S[0][r] * 0.125f;
            float s1 = S[1][r] * 0.125f;
            if (useaw) {
                const size_t awbase = ((size_t)b * 1024 + (qrow0 + g4 * 4 + r)) * 1024 + kb;
                s0 *= aw[awbase + l16];
                s1 *= aw[awbase + 16 + l16];
            }
            if (tail) {
                if (kb + l16 >= 1064) s0 = -1e30f;
                if (kb + 16 + l16 >= 1064) s1 = -1e30f;
            }
            float mx = fmaxf(s0, s1);
#pragma unroll
            for (int off = 1; off < 16; off <<= 1)
                mx = fmaxf(mx, __shfl_xor(mx, off));
            const float mn = fmaxf(m_r[r], mx);
            corr[r] = __expf(m_r[r] - mn);
            m_r[r] = mn;
            const float p0 = __expf(s0 - mn);
            const float p1 = __expf(s1 - mn);
            float rs = p0 + p1;
#pragma unroll
            for (int off = 1; off < 16; off <<= 1)
                rs += __shfl_xor(rs, off);
            l_r[r] = l_r[r] * corr[r] + rs;
            p0v[r] = p0; p1v[r] = p1;
        }
        // P -> wave-private LDS (score layout -> A-frag layout)
#pragma unroll
        for (int r = 0; r < 4; ++r) {
            Ps[w][g4 * 4 + r][l16] = f2bf(p0v[r]);
            Ps[w][g4 * 4 + r][16 + l16] = f2bf(p1v[r]);
        }
        // rescale O
#pragma unroll
        for (int i = 0; i < 4; ++i)
#pragma unroll
            for (int r = 0; r < 4; ++r)
                O[i][r] *= corr[r];
        // PV
        bf16x8 pf = *reinterpret_cast<const bf16x8*>(&Ps[w][l16][g4 * 8]);
#pragma unroll
        for (int sub = 0; sub < 4; ++sub) {
            bf16x8 vf = *reinterpret_cast<const bf16x8*>(&Vs[sub * 16 + l16][g4 * 8]);
            O[sub] = __builtin_amdgcn_mfma_f32_16x16x32_bf16(pf, vf, O[sub], 0, 0, 0);
        }
        __syncthreads();
    }
    // epilogue: normalize and store AO[b*1024+q][h*64+dv] bf16
#pragma unroll
    for (int r = 0; r < 4; ++r) {
        const float inv = 1.0f / l_r[r];
        const int qg = qrow0 + g4 * 4 + r;
        const size_t base = ((size_t)b * 1024 + qg) * 512 + h * 64;
#pragma unroll
        for (int sub = 0; sub < 4; ++sub)
            AO[base + sub * 16 + l16] = f2bf(O[sub][r] * inv);
    }
}

// ---------------------------------------------------------------------------
// Output GEMM + bias + residual: out(fp32) = AO(bf16) @ WoT^T + bo + queries
// ---------------------------------------------------------------------------
__global__ __launch_bounds__(256) void out_gemm(
    const short* __restrict__ A, const short* __restrict__ BT,
    const float* __restrict__ bias, const float* __restrict__ resid,
    float* __restrict__ out)
{
    __shared__ short As[128][40];
    __shared__ short Bs[128][40];
    const int t = threadIdx.x;
    const int lane = t & 63, w = t >> 6;
    const int wr = w >> 1, wc = w & 1;
    const int l16 = lane & 15, g4 = lane >> 4;
    const int m0 = blockIdx.y * 128, n0 = blockIdx.x * 128;

    f32x4 acc[4][4];
#pragma unroll
    for (int i = 0; i < 4; ++i)
#pragma unroll
        for (int j = 0; j < 4; ++j) acc[i][j] = (f32x4){0.f, 0.f, 0.f, 0.f};

    const int sr = t >> 2, sk = (t & 3) * 8;

    for (int kt = 0; kt < 16; ++kt) {
        const int k0 = kt * 32;
#pragma unroll
        for (int nn = 0; nn < 2; ++nn) {
            const int row = sr + nn * 64;
            *reinterpret_cast<bf16x8*>(&As[row][sk]) =
                *reinterpret_cast<const bf16x8*>(&A[(size_t)(m0 + row) * 512 + k0 + sk]);
            *reinterpret_cast<bf16x8*>(&Bs[row][sk]) =
                *reinterpret_cast<const bf16x8*>(&BT[(size_t)(n0 + row) * 512 + k0 + sk]);
        }
        __syncthreads();
        bf16x8 af[4], bfr[4];
#pragma unroll
        for (int mi = 0; mi < 4; ++mi)
            af[mi] = *reinterpret_cast<const bf16x8*>(&As[wr * 64 + mi * 16 + l16][g4 * 8]);
#pragma unroll
        for (int ni = 0; ni < 4; ++ni)
            bfr[ni] = *reinterpret_cast<const bf16x8*>(&Bs[wc * 64 + ni * 16 + l16][g4 * 8]);
#pragma unroll
        for (int mi = 0; mi < 4; ++mi)
#pragma unroll
            for (int ni = 0; ni < 4; ++ni)
                acc[mi][ni] = __builtin_amdgcn_mfma_f32_16x16x32_bf16(af[mi], bfr[ni], acc[mi][ni], 0, 0, 0);
        __syncthreads();
    }
#pragma unroll
    for (int mi = 0; mi < 4; ++mi) {
#pragma unroll
        for (int ni = 0; ni < 4; ++ni) {
            const int col = n0 + wc * 64 + ni * 16 + l16;
            const float bb = bias[col];
#pragma unroll
            for (int r = 0; r < 4; ++r) {
                const int rowg = m0 + wr * 64 + mi * 16 + g4 * 4 + r;
                out[(size_t)rowg * 512 + col] = acc[mi][ni][r] + bb + resid[(size_t)rowg * 512 + col];
            }
        }
    }
}

// ---------------------------------------------------------------------------
// LayerNorm in-place on d_out, one wave per 512-col row
// ---------------------------------------------------------------------------
__global__ __launch_bounds__(256) void ln_kernel(
    float* __restrict__ x, const float* __restrict__ gamma, const float* __restrict__ beta)
{
    const int row = blockIdx.x * 4 + (threadIdx.x >> 6);
    const int lane = threadIdx.x & 63;
    float* rp = x + (size_t)row * 512;
    const float4 v0 = *reinterpret_cast<const float4*>(&rp[lane * 4]);
    const float4 v1 = *reinterpret_cast<const float4*>(&rp[256 + lane * 4]);
    float s = v0.x + v0.y + v0.z + v0.w + v1.x + v1.y + v1.z + v1.w;
    float sq = v0.x * v0.x + v0.y * v0.y + v0.z * v0.z + v0.w * v0.w
             + v1.x * v1.x + v1.y * v1.y + v1.z * v1.z + v1.w * v1.w;
#pragma unroll
    for (int off = 1; off < 64; off <<= 1) {
        s += __shfl_xor(s, off);
        sq += __shfl_xor(sq, off);
    }
    const float mu = s * (1.f / 512.f);
    const float var = sq * (1.f / 512.f) - mu * mu;
    const float inv = rsqrtf(var + 1e-3f);
    const float4 g0 = *reinterpret_cast<const float4*>(&gamma[lane * 4]);
    const float4 g1 = *reinterpret_cast<const float4*>(&gamma[256 + lane * 4]);
    const float4 b0 = *reinterpret_cast<const float4*>(&beta[lane * 4]);
    const float4 b1 = *reinterpret_cast<const float4*>(&beta[256 + lane * 4]);
    float4 o0, o1;
    o0.x = (v0.x - mu) * inv * g0.x + b0.x;
    o0.y = (v0.y - mu) * inv * g0.y + b0.y;
    o0.z = (v0.z - mu) * inv * g0.z + b0.z;
    o0.w = (v0.w - mu) * inv * g0.w + b0.w;
    o1.x = (v1.x - mu) * inv * g1.x + b1.x;
    o1.y = (v1.y - mu) * inv * g1.y + b1.y;
    o1.z = (v1.z - mu) * inv * g1.z + b1.z;
    o1.w = (v1.w - mu) * inv * g1.w + b1.w;
    *reinterpret_cast<float4*>(&rp[lane * 4]) = o0;
    *reinterpret_cast<float4*>(&rp[256 + lane * 4]) = o1;
}

// ---------------------------------------------------------------------------
extern "C" void kernel_launch(void* const* d_in, const int* in_sizes, int n_in,
                              void* d_out, int out_size, void* d_ws, size_t ws_size,
                              hipStream_t stream) {
    const float* queries = (const float*)d_in[0];
    const float* keys    = (const float*)d_in[1];
    const float* values  = (const float*)d_in[2];
    const float* aw      = (const float*)d_in[3];
    const float* Wq = (const float*)d_in[4];
    const float* bq = (const float*)d_in[5];
    const float* Wk = (const float*)d_in[6];
    const float* bk = (const float*)d_in[7];
    const float* Wv = (const float*)d_in[8];
    const float* bv = (const float*)d_in[9];
    const float* Wo = (const float*)d_in[10];
    const float* bo = (const float*)d_in[11];
    const float* memK = (const float*)d_in[12];
    const float* memV = (const float*)d_in[13];
    const float* gamma = (const float*)d_in[14];
    const float* beta  = (const float*)d_in[15];
    float* out = (float*)d_out;

    char* ws = (char*)d_ws;
    short* WqT = (short*)(ws + 0);
    short* WkT = (short*)(ws + 524288);
    short* WvT = (short*)(ws + 1048576);
    short* WoT = (short*)(ws + 1572864);
    short* Qb  = (short*)(ws + 2097152);
    short* Kb  = (short*)(ws + 2097152 + 16777216);
    short* Vb  = (short*)(ws + 2097152 + 16777216 + 17432576);
    short* AO  = (short*)(ws + 2097152 + 16777216 + 2 * 17432576);

    wt_kernel<<<dim3(8, 8, 4), 256, 0, stream>>>(Wq, Wk, Wv, Wo, WqT, WkT, WvT, WoT);
    mem_kernel<<<dim3(1280), 256, 0, stream>>>(memK, memV, Kb, Vb);
    proj_gemm<<<dim3(4, 128), 256, 0, stream>>>(queries, WqT, bq, Qb, 1024);
    proj_gemm<<<dim3(4, 128), 256, 0, stream>>>(keys, WkT, bk, Kb, 1064);
    proj_gemm<<<dim3(4, 128), 256, 0, stream>>>(values, WvT, bv, Vb, 1064);
    attn_kernel<<<dim3(8, 16, 16), 256, 0, stream>>>(Qb, Kb, Vb, aw, AO);
    out_gemm<<<dim3(4, 128), 256, 0, stream>>>(AO, WoT, bo, queries, out);
    ln_kernel<<<dim3(4096), 256, 0, stream>>>(out, gamma, beta);
}

// Round 3
// 419.013 us; speedup vs baseline: 1.3237x; 1.3237x over previous
//
#include <hip/hip_runtime.h>
#include <hip/hip_bf16.h>
#include <math.h>

typedef __attribute__((ext_vector_type(8))) short bf16x8;
typedef __attribute__((ext_vector_type(4))) short s16x4;
typedef __attribute__((ext_vector_type(4))) float f32x4;

static __device__ __forceinline__ short f2bf(float f) {
    union { float f; unsigned u; } v; v.f = f;
    unsigned r = v.u + 0x7FFFu + ((v.u >> 16) & 1u);
    return (short)(r >> 16);
}

// ---------------------------------------------------------------------------
// Weight transpose + fp32->bf16:  WT[n][k] = bf16(W[k][n]),  512x512 each
// ---------------------------------------------------------------------------
__global__ __launch_bounds__(256) void wt_kernel(
    const float* __restrict__ Wq, const float* __restrict__ Wk,
    const float* __restrict__ Wv, const float* __restrict__ Wo,
    short* __restrict__ WqT, short* __restrict__ WkT,
    short* __restrict__ WvT, short* __restrict__ WoT)
{
    __shared__ short lds[64][65];
    const float* src; short* dst;
    if (blockIdx.z == 0)      { src = Wq; dst = WqT; }
    else if (blockIdx.z == 1) { src = Wk; dst = WkT; }
    else if (blockIdx.z == 2) { src = Wv; dst = WvT; }
    else                      { src = Wo; dst = WoT; }
    const int kb = blockIdx.x * 64, nb = blockIdx.y * 64;
    const int t = threadIdx.x;
    const int c = t & 63, r0 = t >> 6;
#pragma unroll
    for (int rr = 0; rr < 16; ++rr) {
        const int r = r0 * 16 + rr;
        lds[c][r] = f2bf(src[(size_t)(kb + r) * 512 + nb + c]);
    }
    __syncthreads();
#pragma unroll
    for (int rr = 0; rr < 16; ++rr) {
        const int n = r0 * 16 + rr;
        dst[(size_t)(nb + n) * 512 + kb + c] = lds[n][c];
    }
}

// ---------------------------------------------------------------------------
// Memory slots: Kb rows 1024..1063 = sqrt(64)*memK; VbT cols 1024..1063
// Kb: [b*8+h][1064][64] bf16; VbT: [b*8+h][64][1088] bf16
// ---------------------------------------------------------------------------
__global__ __launch_bounds__(256) void mem_kernel(
    const float* __restrict__ memK, const float* __restrict__ memV,
    short* __restrict__ Kb, short* __restrict__ VbT)
{
    const int idx = blockIdx.x * 256 + threadIdx.x;
    if (idx >= 16 * 8 * 40 * 64) return;
    const int d = idx & 63;
    const int m = (idx >> 6) % 40;
    const int h = (idx / 2560) & 7;
    const int b = idx / 20480;
    const int src = m * 512 + h * 64 + d;
    const int bh = b * 8 + h;
    Kb[((size_t)bh * 1064 + 1024 + m) * 64 + d] = f2bf(8.0f * memK[src]);
    VbT[((size_t)bh * 64 + d) * 1088 + 1024 + m] = f2bf(sqrtf(40.0f) * memV[src]);
}

// ---------------------------------------------------------------------------
// Projection GEMM: A(fp32 [16384][512]) @ BT^T + bias -> bf16
// vmode==0: out[b,h,n,d] with row count OUTROWS ; vmode==1: out[b,h,d][1088]+n
// ---------------------------------------------------------------------------
__global__ __launch_bounds__(256) void proj_gemm(
    const float* __restrict__ A, const short* __restrict__ BT,
    const float* __restrict__ bias, short* __restrict__ out, int OUTROWS, int vmode)
{
    __shared__ short As[128][40];
    __shared__ short Bs[128][40];
    const int t = threadIdx.x;
    const int lane = t & 63, w = t >> 6;
    const int wr = w >> 1, wc = w & 1;
    const int l16 = lane & 15, g4 = lane >> 4;
    const int m0 = blockIdx.y * 128, n0 = blockIdx.x * 128;

    f32x4 acc[4][4];
#pragma unroll
    for (int i = 0; i < 4; ++i)
#pragma unroll
        for (int j = 0; j < 4; ++j) acc[i][j] = (f32x4){0.f, 0.f, 0.f, 0.f};

    const int sar = t >> 3, sak = (t & 7) * 4;
    const int sbr = t >> 2, sbk = (t & 3) * 8;

    for (int kt = 0; kt < 16; ++kt) {
        const int k0 = kt * 32;
#pragma unroll
        for (int rr = 0; rr < 4; ++rr) {
            const int row = sar + rr * 32;
            const float4 v = *reinterpret_cast<const float4*>(&A[(size_t)(m0 + row) * 512 + k0 + sak]);
            s16x4 bv; bv.x = f2bf(v.x); bv.y = f2bf(v.y); bv.z = f2bf(v.z); bv.w = f2bf(v.w);
            *reinterpret_cast<s16x4*>(&As[row][sak]) = bv;
        }
#pragma unroll
        for (int nn = 0; nn < 2; ++nn) {
            const int nrow = sbr + nn * 64;
            *reinterpret_cast<bf16x8*>(&Bs[nrow][sbk]) =
                *reinterpret_cast<const bf16x8*>(&BT[(size_t)(n0 + nrow) * 512 + k0 + sbk]);
        }
        __syncthreads();
        bf16x8 af[4], bfr[4];
#pragma unroll
        for (int mi = 0; mi < 4; ++mi)
            af[mi] = *reinterpret_cast<const bf16x8*>(&As[wr * 64 + mi * 16 + l16][g4 * 8]);
#pragma unroll
        for (int ni = 0; ni < 4; ++ni)
            bfr[ni] = *reinterpret_cast<const bf16x8*>(&Bs[wc * 64 + ni * 16 + l16][g4 * 8]);
#pragma unroll
        for (int mi = 0; mi < 4; ++mi)
#pragma unroll
            for (int ni = 0; ni < 4; ++ni)
                acc[mi][ni] = __builtin_amdgcn_mfma_f32_16x16x32_bf16(af[mi], bfr[ni], acc[mi][ni], 0, 0, 0);
        __syncthreads();
    }
#pragma unroll
    for (int mi = 0; mi < 4; ++mi) {
#pragma unroll
        for (int ni = 0; ni < 4; ++ni) {
            const int col = n0 + wc * 64 + ni * 16 + l16;
            const int h = col >> 6, d = col & 63;
            const float bb = bias[col];
#pragma unroll
            for (int r = 0; r < 4; ++r) {
                const int rowg = m0 + wr * 64 + mi * 16 + g4 * 4 + r;
                const int b = rowg >> 10, nn = rowg & 1023;
                const short val = f2bf(acc[mi][ni][r] + bb);
                if (vmode)
                    out[(((size_t)b * 8 + h) * 64 + d) * 1088 + nn] = val;
                else
                    out[(((size_t)b * 8 + h) * OUTROWS + nn) * 64 + d] = val;
            }
        }
    }
}

// ---------------------------------------------------------------------------
// Flash attention: 2048 blocks (XCD-swizzled), 4 waves, 64 q-rows/block.
// KVBLK=64, 17 tiles.  aw modulates k<1024; mask k>=1064.
// ---------------------------------------------------------------------------
__global__ __launch_bounds__(256) void attn_kernel(
    const short* __restrict__ Qb, const short* __restrict__ Kb,
    const short* __restrict__ VbT, const float* __restrict__ aw,
    short* __restrict__ AO)
{
    __shared__ short Ks[64][72];
    __shared__ short Vs[64][72];       // [dv][k]
    __shared__ short Ps[4][16][72];    // wave-private P tiles [q][k]

    // XCD swizzle: the 8 heads of one (b,qt) group land on the same XCD
    const int n = blockIdx.x;
    const int xcd = n & 7, s_ = n >> 3, j = s_ & 7, gh = s_ >> 3;
    const int g = gh * 8 + xcd;        // 0..255 = b*16+qt
    const int h = j, qt = g & 15, b = g >> 4;
    const int bh = b * 8 + h;
    const int t = threadIdx.x;
    const int lane = t & 63, w = t >> 6;
    const int l16 = lane & 15, g4 = lane >> 4;
    const int qrow0 = qt * 64 + w * 16;

    bf16x8 qf0, qf1;
    {
        const short* qp = Qb + ((size_t)bh * 1024 + qrow0 + l16) * 64 + g4 * 8;
        qf0 = *reinterpret_cast<const bf16x8*>(qp);
        qf1 = *reinterpret_cast<const bf16x8*>(qp + 32);
    }

    f32x4 O[4];
#pragma unroll
    for (int i = 0; i < 4; ++i) O[i] = (f32x4){0.f, 0.f, 0.f, 0.f};
    float m_r[4] = {-1e30f, -1e30f, -1e30f, -1e30f};
    float l_r[4] = {0.f, 0.f, 0.f, 0.f};

    const int str = t >> 2;            // staging row 0..63
    const int stc = (t & 3) * 16;      // 0,16,32,48 (shorts)

    for (int kt = 0; kt < 17; ++kt) {
        const int kb = kt * 64;
        const bool useaw = (kb < 1024);
        // prefetch aw for this tile (coalesced; hides under staging+QK^T)
        float awv[4][4];
        if (useaw) {
#pragma unroll
            for (int r = 0; r < 4; ++r) {
                const size_t awbase = ((size_t)b * 1024 + qrow0 + g4 * 4 + r) * 1024 + kb + l16;
#pragma unroll
                for (int sub = 0; sub < 4; ++sub)
                    awv[r][sub] = aw[awbase + sub * 16];
            }
        }
        {   // stage K tile [64][64]
            const int rg = kb + str;
            bf16x8 k0 = {0,0,0,0,0,0,0,0}, k1 = {0,0,0,0,0,0,0,0};
            if (rg < 1064) {
                const short* kp = &Kb[((size_t)bh * 1064 + rg) * 64 + stc];
                k0 = *reinterpret_cast<const bf16x8*>(kp);
                k1 = *reinterpret_cast<const bf16x8*>(kp + 8);
            }
            *reinterpret_cast<bf16x8*>(&Ks[str][stc]) = k0;
            *reinterpret_cast<bf16x8*>(&Ks[str][stc + 8]) = k1;
        }
        {   // stage V^T tile [64 dv][64 k] from VbT (vectorized)
            const short* vp = &VbT[((size_t)bh * 64 + str) * 1088 + kb + stc];
            bf16x8 v0 = {0,0,0,0,0,0,0,0}, v1 = {0,0,0,0,0,0,0,0};
            if (kb + stc + 8 <= 1064)  v0 = *reinterpret_cast<const bf16x8*>(vp);
            if (kb + stc + 16 <= 1064) v1 = *reinterpret_cast<const bf16x8*>(vp + 8);
            *reinterpret_cast<bf16x8*>(&Vs[str][stc]) = v0;
            *reinterpret_cast<bf16x8*>(&Vs[str][stc + 8]) = v1;
        }
        __syncthreads();

        // QK^T: S[sub] covers k = kb+sub*16+l16, q rows qrow0+g4*4+r
        f32x4 S[4];
        __builtin_amdgcn_s_setprio(1);
#pragma unroll
        for (int sub = 0; sub < 4; ++sub) {
            bf16x8 kf0 = *reinterpret_cast<const bf16x8*>(&Ks[sub * 16 + l16][g4 * 8]);
            bf16x8 kf1 = *reinterpret_cast<const bf16x8*>(&Ks[sub * 16 + l16][32 + g4 * 8]);
            f32x4 z = {0.f, 0.f, 0.f, 0.f};
            z = __builtin_amdgcn_mfma_f32_16x16x32_bf16(qf0, kf0, z, 0, 0, 0);
            S[sub] = __builtin_amdgcn_mfma_f32_16x16x32_bf16(qf1, kf1, z, 0, 0, 0);
        }
        __builtin_amdgcn_s_setprio(0);

        const bool tail = (kb + 64 > 1064);
        float corr[4], pv[4][4];
#pragma unroll
        for (int r = 0; r < 4; ++r) {
            float sv[4];
#pragma unroll
            for (int sub = 0; sub < 4; ++sub) {
                float x = S[sub][r] * 0.125f;
                if (useaw) x *= awv[r][sub];
                if (tail && (kb + sub * 16 + l16 >= 1064)) x = -1e30f;
                sv[sub] = x;
            }
            float mx = fmaxf(fmaxf(sv[0], sv[1]), fmaxf(sv[2], sv[3]));
#pragma unroll
            for (int off = 1; off < 16; off <<= 1)
                mx = fmaxf(mx, __shfl_xor(mx, off));
            const float mn = fmaxf(m_r[r], mx);
            corr[r] = __expf(m_r[r] - mn);
            m_r[r] = mn;
            float rs = 0.f;
#pragma unroll
            for (int sub = 0; sub < 4; ++sub) {
                pv[r][sub] = __expf(sv[sub] - mn);
                rs += pv[r][sub];
            }
#pragma unroll
            for (int off = 1; off < 16; off <<= 1)
                rs += __shfl_xor(rs, off);
            l_r[r] = l_r[r] * corr[r] + rs;
        }
        // P -> wave-private LDS (score layout -> A-frag layout)
#pragma unroll
        for (int r = 0; r < 4; ++r)
#pragma unroll
            for (int sub = 0; sub < 4; ++sub)
                Ps[w][g4 * 4 + r][sub * 16 + l16] = f2bf(pv[r][sub]);
        // rescale O
#pragma unroll
        for (int i = 0; i < 4; ++i)
#pragma unroll
            for (int r = 0; r < 4; ++r)
                O[i][r] *= corr[r];
        // PV
        bf16x8 pf0 = *reinterpret_cast<const bf16x8*>(&Ps[w][l16][g4 * 8]);
        bf16x8 pf1 = *reinterpret_cast<const bf16x8*>(&Ps[w][l16][32 + g4 * 8]);
        __builtin_amdgcn_s_setprio(1);
#pragma unroll
        for (int sub = 0; sub < 4; ++sub) {
            bf16x8 vf0 = *reinterpret_cast<const bf16x8*>(&Vs[sub * 16 + l16][g4 * 8]);
            bf16x8 vf1 = *reinterpret_cast<const bf16x8*>(&Vs[sub * 16 + l16][32 + g4 * 8]);
            O[sub] = __builtin_amdgcn_mfma_f32_16x16x32_bf16(pf0, vf0, O[sub], 0, 0, 0);
            O[sub] = __builtin_amdgcn_mfma_f32_16x16x32_bf16(pf1, vf1, O[sub], 0, 0, 0);
        }
        __builtin_amdgcn_s_setprio(0);
        __syncthreads();
    }
    // epilogue: normalize and store AO[b*1024+q][h*64+dv] bf16
#pragma unroll
    for (int r = 0; r < 4; ++r) {
        const float inv = 1.0f / l_r[r];
        const int qg = qrow0 + g4 * 4 + r;
        const size_t base = ((size_t)b * 1024 + qg) * 512 + h * 64;
#pragma unroll
        for (int sub = 0; sub < 4; ++sub)
            AO[base + sub * 16 + l16] = f2bf(O[sub][r] * inv);
    }
}

// ---------------------------------------------------------------------------
// Output GEMM + bias + residual: out(fp32) = AO(bf16) @ WoT^T + bo + queries
// ---------------------------------------------------------------------------
__global__ __launch_bounds__(256) void out_gemm(
    const short* __restrict__ A, const short* __restrict__ BT,
    const float* __restrict__ bias, const float* __restrict__ resid,
    float* __restrict__ out)
{
    __shared__ short As[128][40];
    __shared__ short Bs[128][40];
    const int t = threadIdx.x;
    const int lane = t & 63, w = t >> 6;
    const int wr = w >> 1, wc = w & 1;
    const int l16 = lane & 15, g4 = lane >> 4;
    const int m0 = blockIdx.y * 128, n0 = blockIdx.x * 128;

    f32x4 acc[4][4];
#pragma unroll
    for (int i = 0; i < 4; ++i)
#pragma unroll
        for (int j = 0; j < 4; ++j) acc[i][j] = (f32x4){0.f, 0.f, 0.f, 0.f};

    const int sr = t >> 2, sk = (t & 3) * 8;

    for (int kt = 0; kt < 16; ++kt) {
        const int k0 = kt * 32;
#pragma unroll
        for (int nn = 0; nn < 2; ++nn) {
            const int row = sr + nn * 64;
            *reinterpret_cast<bf16x8*>(&As[row][sk]) =
                *reinterpret_cast<const bf16x8*>(&A[(size_t)(m0 + row) * 512 + k0 + sk]);
            *reinterpret_cast<bf16x8*>(&Bs[row][sk]) =
                *reinterpret_cast<const bf16x8*>(&BT[(size_t)(n0 + row) * 512 + k0 + sk]);
        }
        __syncthreads();
        bf16x8 af[4], bfr[4];
#pragma unroll
        for (int mi = 0; mi < 4; ++mi)
            af[mi] = *reinterpret_cast<const bf16x8*>(&As[wr * 64 + mi * 16 + l16][g4 * 8]);
#pragma unroll
        for (int ni = 0; ni < 4; ++ni)
            bfr[ni] = *reinterpret_cast<const bf16x8*>(&Bs[wc * 64 + ni * 16 + l16][g4 * 8]);
#pragma unroll
        for (int mi = 0; mi < 4; ++mi)
#pragma unroll
            for (int ni = 0; ni < 4; ++ni)
                acc[mi][ni] = __builtin_amdgcn_mfma_f32_16x16x32_bf16(af[mi], bfr[ni], acc[mi][ni], 0, 0, 0);
        __syncthreads();
    }
#pragma unroll
    for (int mi = 0; mi < 4; ++mi) {
#pragma unroll
        for (int ni = 0; ni < 4; ++ni) {
            const int col = n0 + wc * 64 + ni * 16 + l16;
            const float bb = bias[col];
#pragma unroll
            for (int r = 0; r < 4; ++r) {
                const int rowg = m0 + wr * 64 + mi * 16 + g4 * 4 + r;
                out[(size_t)rowg * 512 + col] = acc[mi][ni][r] + bb + resid[(size_t)rowg * 512 + col];
            }
        }
    }
}

// ---------------------------------------------------------------------------
// LayerNorm in-place on d_out, one wave per 512-col row
// ---------------------------------------------------------------------------
__global__ __launch_bounds__(256) void ln_kernel(
    float* __restrict__ x, const float* __restrict__ gamma, const float* __restrict__ beta)
{
    const int row = blockIdx.x * 4 + (threadIdx.x >> 6);
    const int lane = threadIdx.x & 63;
    float* rp = x + (size_t)row * 512;
    const float4 v0 = *reinterpret_cast<const float4*>(&rp[lane * 4]);
    const float4 v1 = *reinterpret_cast<const float4*>(&rp[256 + lane * 4]);
    float s = v0.x + v0.y + v0.z + v0.w + v1.x + v1.y + v1.z + v1.w;
    float sq = v0.x * v0.x + v0.y * v0.y + v0.z * v0.z + v0.w * v0.w
             + v1.x * v1.x + v1.y * v1.y + v1.z * v1.z + v1.w * v1.w;
#pragma unroll
    for (int off = 1; off < 64; off <<= 1) {
        s += __shfl_xor(s, off);
        sq += __shfl_xor(sq, off);
    }
    const float mu = s * (1.f / 512.f);
    const float var = sq * (1.f / 512.f) - mu * mu;
    const float inv = rsqrtf(var + 1e-3f);
    const float4 g0 = *reinterpret_cast<const float4*>(&gamma[lane * 4]);
    const float4 g1 = *reinterpret_cast<const float4*>(&gamma[256 + lane * 4]);
    const float4 b0 = *reinterpret_cast<const float4*>(&beta[lane * 4]);
    const float4 b1 = *reinterpret_cast<const float4*>(&beta[256 + lane * 4]);
    float4 o0, o1;
    o0.x = (v0.x - mu) * inv * g0.x + b0.x;
    o0.y = (v0.y - mu) * inv * g0.y + b0.y;
    o0.z = (v0.z - mu) * inv * g0.z + b0.z;
    o0.w = (v0.w - mu) * inv * g0.w + b0.w;
    o1.x = (v1.x - mu) * inv * g1.x + b1.x;
    o1.y = (v1.y - mu) * inv * g1.y + b1.y;
    o1.z = (v1.z - mu) * inv * g1.z + b1.z;
    o1.w = (v1.w - mu) * inv * g1.w + b1.w;
    *reinterpret_cast<float4*>(&rp[lane * 4]) = o0;
    *reinterpret_cast<float4*>(&rp[256 + lane * 4]) = o1;
}

// ---------------------------------------------------------------------------
extern "C" void kernel_launch(void* const* d_in, const int* in_sizes, int n_in,
                              void* d_out, int out_size, void* d_ws, size_t ws_size,
                              hipStream_t stream) {
    const float* queries = (const float*)d_in[0];
    const float* keys    = (const float*)d_in[1];
    const float* values  = (const float*)d_in[2];
    const float* aw      = (const float*)d_in[3];
    const float* Wq = (const float*)d_in[4];
    const float* bq = (const float*)d_in[5];
    const float* Wk = (const float*)d_in[6];
    const float* bk = (const float*)d_in[7];
    const float* Wv = (const float*)d_in[8];
    const float* bv = (const float*)d_in[9];
    const float* Wo = (const float*)d_in[10];
    const float* bo = (const float*)d_in[11];
    const float* memK = (const float*)d_in[12];
    const float* memV = (const float*)d_in[13];
    const float* gamma = (const float*)d_in[14];
    const float* beta  = (const float*)d_in[15];
    float* out = (float*)d_out;

    char* ws = (char*)d_ws;
    short* WqT = (short*)(ws + 0);
    short* WkT = (short*)(ws + 524288);
    short* WvT = (short*)(ws + 1048576);
    short* WoT = (short*)(ws + 1572864);
    short* Qb  = (short*)(ws + 2097152);                       // 16.78 MB
    short* Kb  = (short*)(ws + 2097152 + 16777216);            // 17.43 MB
    short* VbT = (short*)(ws + 2097152 + 16777216 + 17432576); // 17.83 MB
    short* AO  = (short*)(ws + 2097152 + 16777216 + 17432576 + 17825792);

    wt_kernel<<<dim3(8, 8, 4), 256, 0, stream>>>(Wq, Wk, Wv, Wo, WqT, WkT, WvT, WoT);
    mem_kernel<<<dim3(1280), 256, 0, stream>>>(memK, memV, Kb, VbT);
    proj_gemm<<<dim3(4, 128), 256, 0, stream>>>(queries, WqT, bq, Qb, 1024, 0);
    proj_gemm<<<dim3(4, 128), 256, 0, stream>>>(keys, WkT, bk, Kb, 1064, 0);
    proj_gemm<<<dim3(4, 128), 256, 0, stream>>>(values, WvT, bv, VbT, 1064, 1);
    attn_kernel<<<dim3(2048), 256, 0, stream>>>(Qb, Kb, VbT, aw, AO);
    out_gemm<<<dim3(4, 128), 256, 0, stream>>>(AO, WoT, bo, queries, out);
    ln_kernel<<<dim3(4096), 256, 0, stream>>>(out, gamma, beta);
}